// Round 7
// baseline (52.557 us; speedup 1.0000x reference)
//
#include <hip/hip_runtime.h>
#include <math.h>

#define CC 512
#define HH 256
#define WW 256
#define NT 1024           // 16 waves per block
#define NW (NT / 64)      // 16 bands
#define BH (HH / NW)      // 16 rows per band

typedef float f32x4 __attribute__((ext_vector_type(4)));

// DPP move with -inf fill for invalid/masked lanes (old = -inf, bound_ctrl = false)
template<int CTRL, int ROW_MASK>
__device__ __forceinline__ float dpp_ninf(float v) {
    union { float f; int i; } o, s, r;
    o.f = -INFINITY;
    s.f = v;
    r.i = __builtin_amdgcn_update_dpp(o.i, s.i, CTRL, ROW_MASK, 0xF, false);
    return r.f;
}

// 64-lane inclusive max-scan, pure DPP/VALU (verified absmax=0 in rounds 1-5)
__device__ __forceinline__ float wave_incl_max(float v) {
    v = fmaxf(v, dpp_ninf<0x111, 0xF>(v));  // row_shr:1
    v = fmaxf(v, dpp_ninf<0x112, 0xF>(v));  // row_shr:2
    v = fmaxf(v, dpp_ninf<0x114, 0xF>(v));  // row_shr:4
    v = fmaxf(v, dpp_ninf<0x118, 0xF>(v));  // row_shr:8
    v = fmaxf(v, dpp_ninf<0x142, 0xA>(v));  // row_bcast15 -> rows 1,3
    v = fmaxf(v, dpp_ninf<0x143, 0xC>(v));  // row_bcast31 -> rows 2,3
    return v;
}

__device__ __forceinline__ f32x4 fmax4(f32x4 a, f32x4 b) {
    f32x4 r;
    r.x = fmaxf(a.x, b.x);
    r.y = fmaxf(a.y, b.y);
    r.z = fmaxf(a.z, b.z);
    r.w = fmaxf(a.w, b.w);
    return r;
}

// system-scope load: bypass L1/L2, served by MALL/HBM -> second MALL touch
// for the input line (read-only, correctness-safe)
__device__ __forceinline__ f32x4 load_bypass(const float* p) {
    f32x4 d;
    asm volatile("global_load_dwordx4 %0, %1, off sc0 sc1"
                 : "=v"(d) : "v"(p));
    return d;
}

__global__ __launch_bounds__(NT, 4) void corner_pool_kernel(const float* __restrict__ x,
                                                            float* __restrict__ out) {
    __shared__ f32x4 colmax[NW][64];   // 16 KiB: per-band column maxima

    const int t    = threadIdx.x;
    const int lane = t & 63;
    const int w    = t >> 6;           // band index
    const int c    = blockIdx.x;

    const float* band = x   + (size_t)c * HH * WW + (size_t)w * BH * WW;
    float*       ob   = out + (size_t)c * HH * WW + (size_t)w * BH * WW;

    const f32x4 ninf4 = {-INFINITY, -INFINITY, -INFINITY, -INFINITY};

    // ---- pass 1: band column max (normal loads, allocate L2 + MALL touch #1) ----
    f32x4 m = ninf4;
    #pragma unroll
    for (int r = 0; r < BH; ++r) {
        f32x4 u = *(const f32x4*)(band + r * WW + lane * 4);
        m = fmax4(m, u);
    }
    colmax[w][lane] = m;

    // ---- issue pass-2 bypass loads BEFORE the barrier (latency hides under
    //      barrier + carry); volatile asm keeps them ordered here ----
    f32x4 v[BH];                       // 64 VGPRs, fully unrolled, static indices
    #pragma unroll
    for (int r = 0; r < BH; ++r)
        v[r] = load_bypass(band + r * WW + lane * 4);

    __syncthreads();                   // the only barrier

    // ---- carry: max of all earlier bands' column maxima ----
    f32x4 cm = ninf4;
    for (int b = 0; b < w; ++b)
        cm = fmax4(cm, colmax[b][lane]);

    // drain our asm loads; sched_barrier stops consumers hoisting above (rule #18)
    asm volatile("s_waitcnt vmcnt(0)" ::: "memory");
    __builtin_amdgcn_sched_barrier(0);

    // ---- pass 2 (registers): column cummax + DPP row scan, NT store ----
    #pragma unroll
    for (int r = 0; r < BH; ++r) {
        cm = fmax4(cm, v[r]);
        float p0 = cm.x;
        float p1 = fmaxf(p0, cm.y);
        float p2 = fmaxf(p1, cm.z);
        float p3 = fmaxf(p2, cm.w);
        float s  = wave_incl_max(p3);
        float e  = dpp_ninf<0x138, 0xF>(s);   // wave_shr:1 -> exclusive prefix
        f32x4 o;
        o.x = 2.0f * fmaxf(e, p0);
        o.y = 2.0f * fmaxf(e, p1);
        o.z = 2.0f * fmaxf(e, p2);
        o.w = 2.0f * fmaxf(e, p3);
        __builtin_nontemporal_store(o, (f32x4*)(ob + (size_t)r * WW + lane * 4));
    }
}

extern "C" void kernel_launch(void* const* d_in, const int* in_sizes, int n_in,
                              void* d_out, int out_size, void* d_ws, size_t ws_size,
                              hipStream_t stream) {
    const float* x = (const float*)d_in[0];
    float* out = (float*)d_out;
    corner_pool_kernel<<<dim3(CC), dim3(NT), 0, stream>>>(x, out);
}

// Round 8
// 46.418 us; speedup vs baseline: 1.1323x; 1.1323x over previous
//
#include <hip/hip_runtime.h>
#include <math.h>

#define CC 512
#define HH 256
#define WW 256
#define NT 1024           // 16 waves per block
#define NW (NT / 64)      // 16 bands
#define BH (HH / NW)      // 16 rows per band

typedef float f32x4 __attribute__((ext_vector_type(4)));

// DPP move with -inf fill for invalid/masked lanes (old = -inf, bound_ctrl = false)
template<int CTRL, int ROW_MASK>
__device__ __forceinline__ float dpp_ninf(float v) {
    union { float f; int i; } o, s, r;
    o.f = -INFINITY;
    s.f = v;
    r.i = __builtin_amdgcn_update_dpp(o.i, s.i, CTRL, ROW_MASK, 0xF, false);
    return r.f;
}

// 64-lane inclusive max-scan, pure DPP/VALU (verified absmax=0 in rounds 1-7)
__device__ __forceinline__ float wave_incl_max(float v) {
    v = fmaxf(v, dpp_ninf<0x111, 0xF>(v));  // row_shr:1
    v = fmaxf(v, dpp_ninf<0x112, 0xF>(v));  // row_shr:2
    v = fmaxf(v, dpp_ninf<0x114, 0xF>(v));  // row_shr:4
    v = fmaxf(v, dpp_ninf<0x118, 0xF>(v));  // row_shr:8
    v = fmaxf(v, dpp_ninf<0x142, 0xA>(v));  // row_bcast15 -> rows 1,3
    v = fmaxf(v, dpp_ninf<0x143, 0xC>(v));  // row_bcast31 -> rows 2,3
    return v;
}

__device__ __forceinline__ f32x4 fmax4(f32x4 a, f32x4 b) {
    f32x4 r;
    r.x = fmaxf(a.x, b.x);
    r.y = fmaxf(a.y, b.y);
    r.z = fmaxf(a.z, b.z);
    r.w = fmaxf(a.w, b.w);
    return r;
}

__global__ __launch_bounds__(NT, 4) void corner_pool_kernel(const float* __restrict__ x,
                                                            float* __restrict__ out) {
    __shared__ f32x4 colmax[NW][64];   // 16 KiB: per-band column maxima

    const int t    = threadIdx.x;
    const int lane = t & 63;
    const int w    = t >> 6;           // band index
    const int c    = blockIdx.x;

    const float* band = x   + (size_t)c * HH * WW + (size_t)w * BH * WW;
    float*       ob   = out + (size_t)c * HH * WW + (size_t)w * BH * WW;

    const f32x4 ninf4 = {-INFINITY, -INFINITY, -INFINITY, -INFINITY};

    // ---- pass 1: load band (single HBM read), band column max ----
    f32x4 v[BH];                       // fully unrolled -> static indices
    f32x4 m = ninf4;
    #pragma unroll
    for (int r = 0; r < BH; ++r) {
        v[r] = *(const f32x4*)(band + r * WW + lane * 4);
        m = fmax4(m, v[r]);
    }
    colmax[w][lane] = m;
    __syncthreads();                   // the only barrier

    // ---- carry: max of all earlier bands' column maxima ----
    f32x4 cm = ninf4;
    for (int b = 0; b < w; ++b)
        cm = fmax4(cm, colmax[b][lane]);

    // ---- pass 2: column cummax + DPP row scan, NT store ----
    #pragma unroll
    for (int r = 0; r < BH; ++r) {
        cm = fmax4(cm, v[r]);
        float p0 = cm.x;
        float p1 = fmaxf(p0, cm.y);
        float p2 = fmaxf(p1, cm.z);
        float p3 = fmaxf(p2, cm.w);
        float s  = wave_incl_max(p3);
        float e  = dpp_ninf<0x138, 0xF>(s);   // wave_shr:1 -> exclusive prefix
        f32x4 o;
        o.x = 2.0f * fmaxf(e, p0);
        o.y = 2.0f * fmaxf(e, p1);
        o.z = 2.0f * fmaxf(e, p2);
        o.w = 2.0f * fmaxf(e, p3);
        __builtin_nontemporal_store(o, (f32x4*)(ob + (size_t)r * WW + lane * 4));
    }
}

extern "C" void kernel_launch(void* const* d_in, const int* in_sizes, int n_in,
                              void* d_out, int out_size, void* d_ws, size_t ws_size,
                              hipStream_t stream) {
    const float* x = (const float*)d_in[0];
    float* out = (float*)d_out;
    corner_pool_kernel<<<dim3(CC), dim3(NT), 0, stream>>>(x, out);
}